// Round 5
// baseline (1687.369 us; speedup 1.0000x reference)
//
#include <hip/hip_runtime.h>
#include <hip/hip_bf16.h>
#include <math.h>

// Problem constants (SimpleLM): L=6, B=4, T=1024, V=32000, E=768, H=12, D=64
#define L_LAYERS 6
#define BB 4
#define TT 1024
#define VV 32000
#define EE 768
#define HH 12
#define DD 64
#define BT (BB * TT)          // 4096 rows of activations

typedef unsigned short u16;
typedef unsigned int   u32;
typedef __attribute__((ext_vector_type(8))) short short8;
typedef __attribute__((ext_vector_type(8))) unsigned short ushort8v;
typedef __attribute__((ext_vector_type(4))) float f32x4;

__device__ __forceinline__ float b2f_lo(u32 u) { union { u32 i; float f; } c; c.i = u << 16;          return c.f; }
__device__ __forceinline__ float b2f_hi(u32 u) { union { u32 i; float f; } c; c.i = u & 0xffff0000u;  return c.f; }
__device__ __forceinline__ u16  f2b(float f)   { union { float f; u32 i; } c{f}; u32 r = c.i + 0x7fffu + ((c.i >> 16) & 1u); return (u16)(r >> 16); }

__device__ __forceinline__ void gload16(const void* g, void* l) {
    __builtin_amdgcn_global_load_lds(
        (const __attribute__((address_space(1))) void*)g,
        (__attribute__((address_space(3))) void*)l, 16, 0, 0);
}

// ---------------------------------------------------------------------------
// Embedding: x[b,t,e] = tok_emb[idx[b,t], e] + pos_emb[t, e]  (f32 out)
// ---------------------------------------------------------------------------
__global__ __launch_bounds__(256) void embed_kernel(
    const int* __restrict__ idx, const float* __restrict__ tok_emb,
    const float* __restrict__ pos_emb, float* __restrict__ x)
{
    int i = blockIdx.x * 256 + threadIdx.x;          // < BT*EE
    int e  = i % EE;
    int bt = i / EE;
    int t  = bt % TT;
    int tok = idx[bt];
    x[i] = tok_emb[(size_t)tok * EE + e] + pos_emb[(size_t)t * EE + e];
}

// ---------------------------------------------------------------------------
// LayerNorm over last dim (E=768). f32 in, bf16 out. One block per row.
// ---------------------------------------------------------------------------
__global__ __launch_bounds__(256) void ln_kernel(
    const float* __restrict__ X, const float* __restrict__ w,
    const float* __restrict__ b, u16* __restrict__ Y)
{
    const int tid = threadIdx.x;
    const size_t row = blockIdx.x;
    const float* x = X + row * EE;

    float v0 = x[tid], v1 = x[tid + 256], v2 = x[tid + 512];

    __shared__ float red[256];
    red[tid] = v0 + v1 + v2;
    __syncthreads();
    for (int off = 128; off > 0; off >>= 1) {
        if (tid < off) red[tid] += red[tid + off];
        __syncthreads();
    }
    float mean = red[0] * (1.0f / EE);
    __syncthreads();
    float d0 = v0 - mean, d1 = v1 - mean, d2 = v2 - mean;
    red[tid] = d0 * d0 + d1 * d1 + d2 * d2;
    __syncthreads();
    for (int off = 128; off > 0; off >>= 1) {
        if (tid < off) red[tid] += red[tid + off];
        __syncthreads();
    }
    float rstd = rsqrtf(red[0] * (1.0f / EE) + 1e-5f);

    u16* y = Y + row * EE;
    y[tid]       = f2b(d0 * rstd * w[tid]       + b[tid]);
    y[tid + 256] = f2b(d1 * rstd * w[tid + 256] + b[tid + 256]);
    y[tid + 512] = f2b(d2 * rstd * w[tid + 512] + b[tid + 512]);
}

// ---------------------------------------------------------------------------
// Transpose + convert 32x32 tile core: W f32 [K,N] -> Wt bf16 [N,K]
// ---------------------------------------------------------------------------
__device__ __forceinline__ void transpose_tile(
    const float* __restrict__ W, u16* __restrict__ Wt,
    int K, int N, int kt, int nt)
{
    __shared__ float t[32][33];
    const int k0 = kt * 32;
    const int n0 = nt * 32;
    const int c = threadIdx.x & 31;
    const int r = threadIdx.x >> 5;   // 0..7
    #pragma unroll
    for (int i = 0; i < 4; i++)
        t[r + i * 8][c] = W[(size_t)(k0 + r + i * 8) * N + n0 + c];
    __syncthreads();
    #pragma unroll
    for (int i = 0; i < 4; i++) {
        int rr = r + i * 8;
        Wt[(size_t)(n0 + rr) * K + k0 + c] = f2b(t[c][rr]);
    }
}

// Single-matrix transpose (used for head_w)
__global__ __launch_bounds__(256) void transpose_cvt(
    const float* __restrict__ W, u16* __restrict__ Wt, int K, int N)
{
    transpose_tile(W, Wt, K, N, blockIdx.y, blockIdx.x);
}

// Batched per-layer transpose: wq,wk,wv,wo (768x768 each), w1 (768x3072),
// w2 (3072x768) -> wt = [wqT|wkT|wvT|woT|w1T|w2T]. 6912 tiles total.
__global__ __launch_bounds__(256) void transpose_layer(
    const float* __restrict__ wq, const float* __restrict__ wk,
    const float* __restrict__ wv, const float* __restrict__ wo,
    const float* __restrict__ w1, const float* __restrict__ w2,
    u16* __restrict__ wt)
{
    const int t = blockIdx.x;
    if (t < 2304) {                       // 4 x (768x768), 576 tiles each
        const int m = t / 576, r = t % 576;
        const float* Ws[4] = {wq, wk, wv, wo};
        transpose_tile(Ws[m], wt + (size_t)m * 768 * 768, 768, 768, r / 24, r % 24);
    } else if (t < 4608) {                // w1: K=768, N=3072 -> w1T [3072,768]
        const int r = t - 2304;
        transpose_tile(w1, wt + (size_t)4 * 768 * 768, 768, 3072, r / 96, r % 96);
    } else {                              // w2: K=3072, N=768 -> w2T [768,3072]
        const int r = t - 4608;
        transpose_tile(w2, wt + (size_t)4 * 768 * 768 + (size_t)3072 * 768,
                       3072, 768, r / 24, r % 24);
    }
}

// ---------------------------------------------------------------------------
// bf16 MFMA GEMM (128-wide tiles): C = A @ Bt^T (+bias)(+res)(+relu)
// m97-style 2-barrier loop. Used for the narrow (N=768) GEMMs.
// ---------------------------------------------------------------------------
template<int RELU, int RES, int OUTBF, int MFRAG>
__global__ __launch_bounds__(256) void gemm_bf16(
    const u16* __restrict__ A, const u16* __restrict__ Bt,
    const float* __restrict__ bias, const float* __restrict__ res,
    void* __restrict__ Cv, int M, int N, int K)
{
    constexpr int TM = MFRAG * 32;
    __shared__ u16 As[TM * 64];
    __shared__ u16 Bs[128 * 64];

    const int tid  = threadIdx.x;
    const int lane = tid & 63;
    const int w    = tid >> 6;
    const int wr   = w >> 1, wc = w & 1;
    const int m0 = blockIdx.x * TM;
    const int n0 = blockIdx.y * 128;

    const int cs = (lane & 7) ^ (lane >> 3);
    const int rl = lane >> 3;

    int aoff[2 * MFRAG], boff[8];
    const int kq = lane >> 4;
    #pragma unroll
    for (int mi = 0; mi < MFRAG; mi++) {
        int rg = wr * (MFRAG * 16) + mi * 16 + (lane & 15);
        #pragma unroll
        for (int ks = 0; ks < 2; ks++)
            aoff[2 * mi + ks] = rg * 64 + (((ks * 4 + kq) ^ (rg & 7)) * 8);
    }
    #pragma unroll
    for (int ni = 0; ni < 4; ni++) {
        int rg = wc * 64 + ni * 16 + (lane & 15);
        #pragma unroll
        for (int ks = 0; ks < 2; ks++)
            boff[2 * ni + ks] = rg * 64 + (((ks * 4 + kq) ^ (rg & 7)) * 8);
    }

    f32x4 acc[MFRAG][4] = {};

    for (int k0 = 0; k0 < K; k0 += 64) {
        __syncthreads();
        #pragma unroll
        for (int i = 0; i < MFRAG; i++) {
            const int seg = i * 4 + w;
            const int row = seg * 8 + rl;
            gload16(A + (size_t)(m0 + row) * K + k0 + cs * 8, &As[seg * 512]);
        }
        #pragma unroll
        for (int i = 0; i < 4; i++) {
            const int seg = i * 4 + w;
            const int row = seg * 8 + rl;
            gload16(Bt + (size_t)(n0 + row) * K + k0 + cs * 8, &Bs[seg * 512]);
        }
        __syncthreads();
        #pragma unroll
        for (int ks = 0; ks < 2; ks++) {
            short8 af[MFRAG], bfv[4];
            #pragma unroll
            for (int mi = 0; mi < MFRAG; mi++) af[mi] = *(const short8*)&As[aoff[2 * mi + ks]];
            #pragma unroll
            for (int ni = 0; ni < 4; ni++) bfv[ni] = *(const short8*)&Bs[boff[2 * ni + ks]];
            #pragma unroll
            for (int mi = 0; mi < MFRAG; mi++)
                #pragma unroll
                for (int ni = 0; ni < 4; ni++)
                    acc[mi][ni] = __builtin_amdgcn_mfma_f32_16x16x32_bf16(
                        af[mi], bfv[ni], acc[mi][ni], 0, 0, 0);
        }
    }

    const int rbase = m0 + wr * (MFRAG * 16) + (lane >> 4) * 4;
    const int cbase = n0 + wc * 64 + (lane & 15);
    #pragma unroll
    for (int ni = 0; ni < 4; ni++) {
        const int c = cbase + ni * 16;
        const float bv = bias ? bias[c] : 0.0f;
        #pragma unroll
        for (int mi = 0; mi < MFRAG; mi++) {
            const int r = rbase + mi * 16;
            #pragma unroll
            for (int i = 0; i < 4; i++) {
                float v = acc[mi][ni][i] + bv;
                const size_t off = (size_t)(r + i) * N + c;
                if (RES)  v += res[off];
                if (RELU) v = fmaxf(v, 0.0f);
                if (OUTBF) ((u16*)Cv)[off] = f2b(v);
                else       ((float*)Cv)[off] = v;
            }
        }
    }
}

// ---------------------------------------------------------------------------
// 256x256 pipelined bf16 MFMA GEMM (T3+T4+T5): BK=64, 8 waves (2x4),
// per-wave 128x64 output, double-buffered LDS (128 KB), counted vmcnt(8),
// raw s_barrier, setprio around MFMA cluster, XCD-bijective block swizzle.
// Used for the wide GEMMs (N >= 2304). Requires M%256==0, N%256==0, K%64==0,
// K/64 >= 2, grid (M/256)*(N/256) % 8 == 0.
// ---------------------------------------------------------------------------
template<int RELU, int OUTBF>
__global__ __launch_bounds__(512, 2) void gemm256(
    const u16* __restrict__ A, const u16* __restrict__ Bt,
    const float* __restrict__ bias, void* __restrict__ Cv,
    int M, int N, int K)
{
    __shared__ u16 SA[2][256 * 64];
    __shared__ u16 SB[2][256 * 64];

    const int tid  = threadIdx.x;
    const int lane = tid & 63;
    const int w    = tid >> 6;          // 0..7
    const int wr   = w >> 2, wc = w & 3;

    // XCD-aware bijective swizzle (all our grids have nwg % 8 == 0)
    const int gx  = gridDim.x;          // M-tiles (fast dispatch dim)
    const int nwg = gx * gridDim.y;
    const int lin = blockIdx.y * gx + blockIdx.x;
    const int q8  = nwg >> 3;
    const int s   = (lin & 7) * q8 + (lin >> 3);
    const int m0  = (s % gx) * 256;
    const int n0  = (s / gx) * 256;

    const int cs = (lane & 7) ^ (lane >> 3);   // pre-swizzled source chunk
    const int rl = lane >> 3;

    const int lr = lane & 15, kq = lane >> 4;
    int aoff[16], boff[8];
    #pragma unroll
    for (int mi = 0; mi < 8; mi++) {
        int rg = wr * 128 + mi * 16 + lr;
        #pragma unroll
        for (int ks = 0; ks < 2; ks++)
            aoff[2 * mi + ks] = rg * 64 + (((ks * 4 + kq) ^ (rg & 7)) * 8);
    }
    #pragma unroll
    for (int ni = 0; ni < 4; ni++) {
        int rg = wc * 64 + ni * 16 + lr;
        #pragma unroll
        for (int ks = 0; ks < 2; ks++)
            boff[2 * ni + ks] = rg * 64 + (((ks * 4 + kq) ^ (rg & 7)) * 8);
    }

    const int nt = K >> 6;

    // stage K-tile t into buffer bf: 4+4 gload16 per thread (8 VMEM/wave)
    auto STAGE = [&](int t, int bf) {
        const int k0 = t * 64;
        #pragma unroll
        for (int i = 0; i < 4; i++) {
            const int seg = i * 8 + w;
            const int row = seg * 8 + rl;
            gload16(A + (size_t)(m0 + row) * K + k0 + cs * 8, &SA[bf][seg * 512]);
        }
        #pragma unroll
        for (int i = 0; i < 4; i++) {
            const int seg = i * 8 + w;
            const int row = seg * 8 + rl;
            gload16(Bt + (size_t)(n0 + row) * K + k0 + cs * 8, &SB[bf][seg * 512]);
        }
    };

    f32x4 acc[8][4] = {};

    // prologue: two tiles in flight, wait for the first
    STAGE(0, 0);
    STAGE(1, 1);
    asm volatile("s_waitcnt vmcnt(8)" ::: "memory");
    __builtin_amdgcn_s_barrier();
    __builtin_amdgcn_sched_barrier(0);

    for (int t = 0; t < nt; t++) {
        const int cur = t & 1;
        __builtin_amdgcn_s_setprio(1);
        #pragma unroll
        for (int ks = 0; ks < 2; ks++) {
            short8 af[8], bv[4];
            #pragma unroll
            for (int mi = 0; mi < 8; mi++) af[mi] = *(const short8*)&SA[cur][aoff[2 * mi + ks]];
            #pragma unroll
            for (int ni = 0; ni < 4; ni++) bv[ni] = *(const short8*)&SB[cur][boff[2 * ni + ks]];
            #pragma unroll
            for (int mi = 0; mi < 8; mi++)
                #pragma unroll
                for (int ni = 0; ni < 4; ni++)
                    acc[mi][ni] = __builtin_amdgcn_mfma_f32_16x16x32_bf16(
                        af[mi], bv[ni], acc[mi][ni], 0, 0, 0);
        }
        __builtin_amdgcn_s_setprio(0);

        if (t < nt - 1) {
            __builtin_amdgcn_sched_barrier(0);
            __builtin_amdgcn_s_barrier();        // all waves done reading buf[cur]
            __builtin_amdgcn_sched_barrier(0);
            if (t + 2 < nt) {
                STAGE(t + 2, cur);               // refill the buffer just consumed
                asm volatile("s_waitcnt vmcnt(8)" ::: "memory");  // tile t+1 landed
            } else {
                asm volatile("s_waitcnt vmcnt(0)" ::: "memory");
            }
            __builtin_amdgcn_sched_barrier(0);
            __builtin_amdgcn_s_barrier();        // tile t+1 visible to all
            __builtin_amdgcn_sched_barrier(0);
        }
    }

    // epilogue
    const int rbase = m0 + wr * 128 + (lane >> 4) * 4;
    const int cbase = n0 + wc * 64 + lr;
    #pragma unroll
    for (int ni = 0; ni < 4; ni++) {
        const int c = cbase + ni * 16;
        const float bvf = bias ? bias[c] : 0.0f;
        #pragma unroll
        for (int mi = 0; mi < 8; mi++) {
            const int r = rbase + mi * 16;
            #pragma unroll
            for (int i = 0; i < 4; i++) {
                float v = acc[mi][ni][i] + bvf;
                if (RELU) v = fmaxf(v, 0.0f);
                const size_t off = (size_t)(r + i) * N + c;
                if (OUTBF) ((u16*)Cv)[off] = f2b(v);
                else       ((float*)Cv)[off] = v;
            }
        }
    }
}

// ---------------------------------------------------------------------------
// MFMA flash attention: block per (q-tile 64, h, b). 256 threads = 4 waves.
// ---------------------------------------------------------------------------
#define AST 76
__global__ __launch_bounds__(256) void attn_mfma(
    const u16* __restrict__ qkv, u16* __restrict__ O)
{
    const int tid = threadIdx.x;
    const int qi = blockIdx.x;
    const int h  = blockIdx.y;
    const int b  = blockIdx.z;
    const int q0 = qi * 64;

    __shared__ u16 Ks[64 * AST];
    __shared__ u16 Vt[64 * AST];
    __shared__ u16 Ps[64 * AST];   // doubles as Q staging buffer

    const int lane = tid & 63;
    const int w    = tid >> 6;
    const int lr   = lane & 15;
    const int lk   = lane >> 4;

    const int sr = tid >> 2;
    const int sc = tid & 3;

    {
        const u16* src = qkv + (size_t)(b * TT + q0 + sr) * 2304 + h * 64 + sc * 16;
        *(ushort8v*)&Ps[sr * AST + sc * 16]     = *(const ushort8v*)src;
        *(ushort8v*)&Ps[sr * AST + sc * 16 + 8] = *(const ushort8v*)(src + 8);
    }
    __syncthreads();
    short8 aq[2];
    #pragma unroll
    for (int ks = 0; ks < 2; ks++)
        aq[ks] = *(const short8*)&Ps[(w * 16 + lr) * AST + lk * 8 + ks * 32];

    f32x4 oacc[4] = {};
    float m_run[4], l_run[4];
    #pragma unroll
    for (int i = 0; i < 4; i++) { m_run[i] = -3.0e38f; l_run[i] = 0.0f; }

    const int qrow = q0 + w * 16 + lk * 4;
    const int ntile = qi + 1;

    for (int t = 0; t < ntile; t++) {
        const int k0 = t * 64;
        __syncthreads();
        {
            const u16* ksrc = qkv + (size_t)(b * TT + k0 + sr) * 2304 + 768 + h * 64 + sc * 16;
            *(ushort8v*)&Ks[sr * AST + sc * 16]     = *(const ushort8v*)ksrc;
            *(ushort8v*)&Ks[sr * AST + sc * 16 + 8] = *(const ushort8v*)(ksrc + 8);
            const u16* vsrc = ksrc + 768;
            ushort8v v0 = *(const ushort8v*)vsrc;
            ushort8v v1 = *(const ushort8v*)(vsrc + 8);
            #pragma unroll
            for (int j = 0; j < 8; j++) Vt[(sc * 16 + j) * AST + sr]     = v0[j];
            #pragma unroll
            for (int j = 0; j < 8; j++) Vt[(sc * 16 + 8 + j) * AST + sr] = v1[j];
        }
        __syncthreads();

        f32x4 sfrag[4] = {};
        #pragma unroll
        for (int ks = 0; ks < 2; ks++)
            #pragma unroll
            for (int nt = 0; nt < 4; nt++) {
                short8 bk = *(const short8*)&Ks[(nt * 16 + lr) * AST + lk * 8 + ks * 32];
                sfrag[nt] = __builtin_amdgcn_mfma_f32_16x16x32_bf16(aq[ks], bk, sfrag[nt], 0, 0, 0);
            }

        float sv[4][4];
        #pragma unroll
        for (int i = 0; i < 4; i++) {
            float mx = -3.0e38f;
            #pragma unroll
            for (int nt = 0; nt < 4; nt++) {
                float s = sfrag[nt][i] * 0.125f;
                if (t == qi && (k0 + nt * 16 + lr) > (qrow + i)) s = -3.0e38f;
                sv[i][nt] = s;
                mx = fmaxf(mx, s);
            }
            mx = fmaxf(mx, __shfl_xor(mx, 1));
            mx = fmaxf(mx, __shfl_xor(mx, 2));
            mx = fmaxf(mx, __shfl_xor(mx, 4));
            mx = fmaxf(mx, __shfl_xor(mx, 8));
            const float m_new = fmaxf(m_run[i], mx);
            const float scale = __expf(m_run[i] - m_new);
            float rs = 0.0f;
            #pragma unroll
            for (int nt = 0; nt < 4; nt++) {
                float p = __expf(sv[i][nt] - m_new);
                sv[i][nt] = p;
                rs += p;
            }
            rs += __shfl_xor(rs, 1);
            rs += __shfl_xor(rs, 2);
            rs += __shfl_xor(rs, 4);
            rs += __shfl_xor(rs, 8);
            l_run[i] = l_run[i] * scale + rs;
            m_run[i] = m_new;
            #pragma unroll
            for (int dt = 0; dt < 4; dt++) oacc[dt][i] *= scale;
        }

        #pragma unroll
        for (int i = 0; i < 4; i++)
            #pragma unroll
            for (int nt = 0; nt < 4; nt++)
                Ps[(w * 16 + lk * 4 + i) * AST + nt * 16 + lr] = f2b(sv[i][nt]);
        __syncthreads();

        #pragma unroll
        for (int ks = 0; ks < 2; ks++) {
            short8 ap = *(const short8*)&Ps[(w * 16 + lr) * AST + lk * 8 + ks * 32];
            #pragma unroll
            for (int dt = 0; dt < 4; dt++) {
                short8 bv = *(const short8*)&Vt[(dt * 16 + lr) * AST + lk * 8 + ks * 32];
                oacc[dt] = __builtin_amdgcn_mfma_f32_16x16x32_bf16(ap, bv, oacc[dt], 0, 0, 0);
            }
        }
    }

    #pragma unroll
    for (int i = 0; i < 4; i++) {
        const float inv = 1.0f / l_run[i];
        u16* dst = O + (size_t)(b * TT + q0 + w * 16 + lk * 4 + i) * 768 + h * 64 + lr;
        #pragma unroll
        for (int dt = 0; dt < 4; dt++)
            dst[dt * 16] = f2b(oacc[dt][i] * inv);
    }
}

// ---------------------------------------------------------------------------
// Host-side launch
// ---------------------------------------------------------------------------
extern "C" void kernel_launch(void* const* d_in, const int* in_sizes, int n_in,
                              void* d_out, int out_size, void* d_ws, size_t ws_size,
                              hipStream_t stream)
{
    (void)in_sizes; (void)n_in; (void)out_size; (void)ws_size;

    const int*   idx     = (const int*)  d_in[0];
    const float* tok_emb = (const float*)d_in[1];
    const float* pos_emb = (const float*)d_in[2];
    const float* ln1_w   = (const float*)d_in[3];
    const float* ln1_b   = (const float*)d_in[4];
    const float* wq      = (const float*)d_in[5];
    const float* wk      = (const float*)d_in[6];
    const float* wv      = (const float*)d_in[7];
    const float* wo      = (const float*)d_in[8];
    const float* bo      = (const float*)d_in[9];
    const float* ln2_w   = (const float*)d_in[10];
    const float* ln2_b   = (const float*)d_in[11];
    const float* w1      = (const float*)d_in[12];
    const float* b1      = (const float*)d_in[13];
    const float* w2      = (const float*)d_in[14];
    const float* b2      = (const float*)d_in[15];
    const float* lnf_w   = (const float*)d_in[16];
    const float* lnf_b   = (const float*)d_in[17];
    const float* head_w  = (const float*)d_in[18];
    const float* head_b  = (const float*)d_in[19];
    float* out = (float*)d_out;

    // workspace carve: ~112 MB
    const size_t S = (size_t)BT * EE;                 // 3,145,728
    float* x   = (float*)d_ws;                        // f32 [BT,768]
    u16*  qkv  = (u16*)(x + S);                       // bf16 [BT,2304]
    u16*  hb   = qkv + (size_t)BT * 2304;             // bf16 [BT,768]
    u16*  ffh  = hb + S;                              // bf16 [BT,3072]
    u16*  wt   = ffh + (size_t)BT * 3072;             // bf16 weights, reused per layer

    embed_kernel<<<BT * EE / 256, 256, 0, stream>>>(idx, tok_emb, pos_emb, x);

    for (int l = 0; l < L_LAYERS; l++) {
        const size_t oE  = (size_t)l * EE;
        const size_t oEE = (size_t)l * EE * EE;
        const size_t oEF = (size_t)l * EE * 4 * EE;

        // weight prep: all 6 matrices of this layer in one dispatch
        transpose_layer<<<6912, 256, 0, stream>>>(
            wq + oEE, wk + oEE, wv + oEE, wo + oEE, w1 + oEF, w2 + oEF, wt);

        // h = LN1(x)
        ln_kernel<<<BT, 256, 0, stream>>>(x, ln1_w + oE, ln1_b + oE, hb);
        // qkv = h @ [Wq|Wk|Wv]   (bf16 out) — 16x9 = 144 blocks
        gemm256<0, 1><<<dim3(BT / 256, 2304 / 256), 512, 0, stream>>>(
            hb, wt, nullptr, qkv, BT, 2304, 768);
        // h = attention(qkv)  — MFMA flash
        attn_mfma<<<dim3(TT / 64, HH, BB), 256, 0, stream>>>(qkv, hb);
        // x = x + h @ Wo + bo   (TM=64: 384 blocks)
        gemm_bf16<0, 1, 0, 2><<<dim3(BT / 64, 768 / 128), 256, 0, stream>>>(
            hb, wt + (size_t)3 * 768 * 768, bo + oE, x, x, BT, 768, 768);
        // h = LN2(x)
        ln_kernel<<<BT, 256, 0, stream>>>(x, ln2_w + oE, ln2_b + oE, hb);
        // ffh = relu(h @ W1 + b1)  (bf16 out) — 16x12 = 192 blocks
        gemm256<1, 1><<<dim3(BT / 256, 3072 / 256), 512, 0, stream>>>(
            hb, wt + (size_t)4 * 768 * 768, b1 + (size_t)l * 4 * EE, ffh, BT, 3072, 768);
        // x = x + ffh @ W2 + b2   (TM=64: 384 blocks)
        gemm_bf16<0, 1, 0, 2><<<dim3(BT / 64, 768 / 128), 256, 0, stream>>>(
            ffh, wt + (size_t)4 * 768 * 768 + (size_t)3072 * 768, b2 + oE, x, x, BT, 768, 3072);
    }

    // final LN + head
    ln_kernel<<<BT, 256, 0, stream>>>(x, lnf_w, lnf_b, hb);
    transpose_cvt<<<dim3(VV / 32, EE / 32), 256, 0, stream>>>(head_w, wt, EE, VV);
    // head: 16x125 = 2000 blocks
    gemm256<0, 0><<<dim3(BT / 256, VV / 256), 512, 0, stream>>>(
        hb, wt, head_b, out, BT, VV, 768);
}

// Round 6
// 1631.622 us; speedup vs baseline: 1.0342x; 1.0342x over previous
//
#include <hip/hip_runtime.h>
#include <hip/hip_bf16.h>
#include <math.h>

// Problem constants (SimpleLM): L=6, B=4, T=1024, V=32000, E=768, H=12, D=64
#define L_LAYERS 6
#define BB 4
#define TT 1024
#define VV 32000
#define EE 768
#define HH 12
#define DD 64
#define BT (BB * TT)          // 4096 rows of activations

typedef unsigned short u16;
typedef unsigned int   u32;
typedef __attribute__((ext_vector_type(8))) short short8;
typedef __attribute__((ext_vector_type(8))) unsigned short ushort8v;
typedef __attribute__((ext_vector_type(4))) float f32x4;

__device__ __forceinline__ float b2f_lo(u32 u) { union { u32 i; float f; } c; c.i = u << 16;          return c.f; }
__device__ __forceinline__ float b2f_hi(u32 u) { union { u32 i; float f; } c; c.i = u & 0xffff0000u;  return c.f; }
__device__ __forceinline__ u16  f2b(float f)   { union { float f; u32 i; } c{f}; u32 r = c.i + 0x7fffu + ((c.i >> 16) & 1u); return (u16)(r >> 16); }

__device__ __forceinline__ void gload16(const void* g, void* l) {
    __builtin_amdgcn_global_load_lds(
        (const __attribute__((address_space(1))) void*)g,
        (__attribute__((address_space(3))) void*)l, 16, 0, 0);
}

// ---------------------------------------------------------------------------
// Embedding: x[b,t,e] = tok_emb[idx[b,t], e] + pos_emb[t, e]  (f32 out)
// ---------------------------------------------------------------------------
__global__ __launch_bounds__(256) void embed_kernel(
    const int* __restrict__ idx, const float* __restrict__ tok_emb,
    const float* __restrict__ pos_emb, float* __restrict__ x)
{
    int i = blockIdx.x * 256 + threadIdx.x;          // < BT*EE
    int e  = i % EE;
    int bt = i / EE;
    int t  = bt % TT;
    int tok = idx[bt];
    x[i] = tok_emb[(size_t)tok * EE + e] + pos_emb[(size_t)t * EE + e];
}

// ---------------------------------------------------------------------------
// LayerNorm over last dim (E=768). f32 in, bf16 out. One block per row.
// ---------------------------------------------------------------------------
__global__ __launch_bounds__(256) void ln_kernel(
    const float* __restrict__ X, const float* __restrict__ w,
    const float* __restrict__ b, u16* __restrict__ Y)
{
    const int tid = threadIdx.x;
    const size_t row = blockIdx.x;
    const float* x = X + row * EE;

    float v0 = x[tid], v1 = x[tid + 256], v2 = x[tid + 512];

    __shared__ float red[256];
    red[tid] = v0 + v1 + v2;
    __syncthreads();
    for (int off = 128; off > 0; off >>= 1) {
        if (tid < off) red[tid] += red[tid + off];
        __syncthreads();
    }
    float mean = red[0] * (1.0f / EE);
    __syncthreads();
    float d0 = v0 - mean, d1 = v1 - mean, d2 = v2 - mean;
    red[tid] = d0 * d0 + d1 * d1 + d2 * d2;
    __syncthreads();
    for (int off = 128; off > 0; off >>= 1) {
        if (tid < off) red[tid] += red[tid + off];
        __syncthreads();
    }
    float rstd = rsqrtf(red[0] * (1.0f / EE) + 1e-5f);

    u16* y = Y + row * EE;
    y[tid]       = f2b(d0 * rstd * w[tid]       + b[tid]);
    y[tid + 256] = f2b(d1 * rstd * w[tid + 256] + b[tid + 256]);
    y[tid + 512] = f2b(d2 * rstd * w[tid + 512] + b[tid + 512]);
}

// ---------------------------------------------------------------------------
// Transpose + convert 32x32 tile core: W f32 [K,N] -> Wt bf16 [N,K]
// ---------------------------------------------------------------------------
__device__ __forceinline__ void transpose_tile(
    const float* __restrict__ W, u16* __restrict__ Wt,
    int K, int N, int kt, int nt)
{
    __shared__ float t[32][33];
    const int k0 = kt * 32;
    const int n0 = nt * 32;
    const int c = threadIdx.x & 31;
    const int r = threadIdx.x >> 5;   // 0..7
    #pragma unroll
    for (int i = 0; i < 4; i++)
        t[r + i * 8][c] = W[(size_t)(k0 + r + i * 8) * N + n0 + c];
    __syncthreads();
    #pragma unroll
    for (int i = 0; i < 4; i++) {
        int rr = r + i * 8;
        Wt[(size_t)(n0 + rr) * K + k0 + c] = f2b(t[c][rr]);
    }
}

// Single-matrix transpose (used for head_w)
__global__ __launch_bounds__(256) void transpose_cvt(
    const float* __restrict__ W, u16* __restrict__ Wt, int K, int N)
{
    transpose_tile(W, Wt, K, N, blockIdx.y, blockIdx.x);
}

// Batched per-layer transpose: wq,wk,wv,wo (768x768 each), w1 (768x3072),
// w2 (3072x768) -> wt = [wqT|wkT|wvT|woT|w1T|w2T]. 6912 tiles total.
__global__ __launch_bounds__(256) void transpose_layer(
    const float* __restrict__ wq, const float* __restrict__ wk,
    const float* __restrict__ wv, const float* __restrict__ wo,
    const float* __restrict__ w1, const float* __restrict__ w2,
    u16* __restrict__ wt)
{
    const int t = blockIdx.x;
    if (t < 2304) {                       // 4 x (768x768), 576 tiles each
        const int m = t / 576, r = t % 576;
        const float* Ws[4] = {wq, wk, wv, wo};
        transpose_tile(Ws[m], wt + (size_t)m * 768 * 768, 768, 768, r / 24, r % 24);
    } else if (t < 4608) {                // w1: K=768, N=3072 -> w1T [3072,768]
        const int r = t - 2304;
        transpose_tile(w1, wt + (size_t)4 * 768 * 768, 768, 3072, r / 96, r % 96);
    } else {                              // w2: K=3072, N=768 -> w2T [768,3072]
        const int r = t - 4608;
        transpose_tile(w2, wt + (size_t)4 * 768 * 768 + (size_t)3072 * 768,
                       3072, 768, r / 24, r % 24);
    }
}

// ---------------------------------------------------------------------------
// bf16 MFMA GEMM (128-wide tiles): C = A @ Bt^T (+bias)(+res)(+relu)
// m97-style 2-barrier loop. Used for the narrow (N=768) GEMMs.
// ---------------------------------------------------------------------------
template<int RELU, int RES, int OUTBF, int MFRAG>
__global__ __launch_bounds__(256) void gemm_bf16(
    const u16* __restrict__ A, const u16* __restrict__ Bt,
    const float* __restrict__ bias, const float* __restrict__ res,
    void* __restrict__ Cv, int M, int N, int K)
{
    constexpr int TM = MFRAG * 32;
    __shared__ u16 As[TM * 64];
    __shared__ u16 Bs[128 * 64];

    const int tid  = threadIdx.x;
    const int lane = tid & 63;
    const int w    = tid >> 6;
    const int wr   = w >> 1, wc = w & 1;
    const int m0 = blockIdx.x * TM;
    const int n0 = blockIdx.y * 128;

    const int cs = (lane & 7) ^ (lane >> 3);
    const int rl = lane >> 3;

    int aoff[2 * MFRAG], boff[8];
    const int kq = lane >> 4;
    #pragma unroll
    for (int mi = 0; mi < MFRAG; mi++) {
        int rg = wr * (MFRAG * 16) + mi * 16 + (lane & 15);
        #pragma unroll
        for (int ks = 0; ks < 2; ks++)
            aoff[2 * mi + ks] = rg * 64 + (((ks * 4 + kq) ^ (rg & 7)) * 8);
    }
    #pragma unroll
    for (int ni = 0; ni < 4; ni++) {
        int rg = wc * 64 + ni * 16 + (lane & 15);
        #pragma unroll
        for (int ks = 0; ks < 2; ks++)
            boff[2 * ni + ks] = rg * 64 + (((ks * 4 + kq) ^ (rg & 7)) * 8);
    }

    f32x4 acc[MFRAG][4] = {};

    for (int k0 = 0; k0 < K; k0 += 64) {
        __syncthreads();
        #pragma unroll
        for (int i = 0; i < MFRAG; i++) {
            const int seg = i * 4 + w;
            const int row = seg * 8 + rl;
            gload16(A + (size_t)(m0 + row) * K + k0 + cs * 8, &As[seg * 512]);
        }
        #pragma unroll
        for (int i = 0; i < 4; i++) {
            const int seg = i * 4 + w;
            const int row = seg * 8 + rl;
            gload16(Bt + (size_t)(n0 + row) * K + k0 + cs * 8, &Bs[seg * 512]);
        }
        __syncthreads();
        #pragma unroll
        for (int ks = 0; ks < 2; ks++) {
            short8 af[MFRAG], bfv[4];
            #pragma unroll
            for (int mi = 0; mi < MFRAG; mi++) af[mi] = *(const short8*)&As[aoff[2 * mi + ks]];
            #pragma unroll
            for (int ni = 0; ni < 4; ni++) bfv[ni] = *(const short8*)&Bs[boff[2 * ni + ks]];
            #pragma unroll
            for (int mi = 0; mi < MFRAG; mi++)
                #pragma unroll
                for (int ni = 0; ni < 4; ni++)
                    acc[mi][ni] = __builtin_amdgcn_mfma_f32_16x16x32_bf16(
                        af[mi], bfv[ni], acc[mi][ni], 0, 0, 0);
        }
    }

    const int rbase = m0 + wr * (MFRAG * 16) + (lane >> 4) * 4;
    const int cbase = n0 + wc * 64 + (lane & 15);
    #pragma unroll
    for (int ni = 0; ni < 4; ni++) {
        const int c = cbase + ni * 16;
        const float bv = bias ? bias[c] : 0.0f;
        #pragma unroll
        for (int mi = 0; mi < MFRAG; mi++) {
            const int r = rbase + mi * 16;
            #pragma unroll
            for (int i = 0; i < 4; i++) {
                float v = acc[mi][ni][i] + bv;
                const size_t off = (size_t)(r + i) * N + c;
                if (RES)  v += res[off];
                if (RELU) v = fmaxf(v, 0.0f);
                if (OUTBF) ((u16*)Cv)[off] = f2b(v);
                else       ((float*)Cv)[off] = v;
            }
        }
    }
}

// ---------------------------------------------------------------------------
// 256x256 8-phase pipelined bf16 MFMA GEMM (T2+T3+T4+T5, m201 structure).
// BK=64, 512 threads = 8 waves (2Mx4N), per-wave 128x64 C. 4 phases per
// K-tile, each = {ds-read quadrant | stage 1 half-tile} -> bar -> lgkm0 ->
// setprio(1) 16 MFMA setprio(0) -> bar. vmcnt(6) once per K-tile (phase 4).
// LDS 128 KiB: per parity, A/B stored as two 128-row halves with permuted
// row order so each half is contiguous & freed exactly one phase before
// its re-stage. A: lds_row = global_row w/ bits6,7 swapped. B: rotate 7..5.
// Chunk-XOR swizzle (LDS[r][c] = G[grow(r)][c ^ (r&7)]) as in gemm_bf16.
// Requires M%256==0, N%256==0, K%64==0, K/64>=2, nwg%8==0.
// ---------------------------------------------------------------------------
template<int RELU, int OUTBF>
__global__ __launch_bounds__(512, 2) void gemm8p(
    const u16* __restrict__ A, const u16* __restrict__ Bt,
    const float* __restrict__ bias, void* __restrict__ Cv,
    int M, int N, int K)
{
    __shared__ u16 SA[2][256 * 64];
    __shared__ u16 SB[2][256 * 64];

    const int tid  = threadIdx.x;
    const int lane = tid & 63;
    const int w    = tid >> 6;          // 0..7
    const int wr   = w >> 2, wc = w & 3;
    const int lr   = lane & 15, kq = lane >> 4;
    const int lr7  = lr & 7;

    // XCD-aware bijective swizzle (nwg % 8 == 0 for all our grids)
    const int gx  = gridDim.x;          // M-tiles (fast)
    const int nwg = gx * gridDim.y;
    const int lin = blockIdx.y * gx + blockIdx.x;
    const int q8  = nwg >> 3;
    const int s   = (lin & 7) * q8 + (lin >> 3);
    const int m0  = (s % gx) * 256;
    const int n0  = (s / gx) * 256;

    const int cs = (lane & 7) ^ (lane >> 3);   // pre-swizzled source chunk
    const int rl = lane >> 3;

    const int nt = K >> 6;

    // stage A half h of K-tile tt (rows: lds_row = swap bits6,7 of global)
    auto STAGE_A = [&](int tt, int h) {
        u16* dst = &SA[tt & 1][0];
        const int k0 = tt << 6;
        #pragma unroll
        for (int j = 0; j < 2; ++j) {
            const int seg   = j * 8 + w;
            const int rbase = h * 128 + seg * 8;    // uniform per instr
            const int r     = rbase + rl;
            const int grow  = (r & 63) | ((r & 128) >> 1) | ((r & 64) << 1);
            gload16(A + (size_t)(m0 + grow) * K + k0 + cs * 8, dst + rbase * 64);
        }
    };
    // stage B half h (rows: global bits7..5 = lds bits 6,5,7)
    auto STAGE_B = [&](int tt, int h) {
        u16* dst = &SB[tt & 1][0];
        const int k0 = tt << 6;
        #pragma unroll
        for (int j = 0; j < 2; ++j) {
            const int seg   = j * 8 + w;
            const int rbase = h * 128 + seg * 8;
            const int r     = rbase + rl;
            const int grow  = (r & 31) | ((r & 96) << 1) | ((r & 128) >> 2);
            gload16(Bt + (size_t)(n0 + grow) * K + k0 + cs * 8, dst + rbase * 64);
        }
    };

    // prologue: tile0 fully + 3 halves of tile1 (A-h1 staged in t=0 phase 1)
    STAGE_A(0, 0); STAGE_A(0, 1); STAGE_B(0, 0); STAGE_B(0, 1);
    STAGE_A(1, 0); STAGE_B(1, 0); STAGE_B(1, 1);
    asm volatile("s_waitcnt vmcnt(6)" ::: "memory");
    __builtin_amdgcn_s_barrier();

    f32x4 acc[8][4] = {};

    for (int t = 0; t < nt; ++t) {
        const int p = t & 1;
        const u16* a0p = &SA[p][0] + wr * 4096 + lr * 64;
        const u16* b0p = &SB[p][0] + wc * 2048 + lr * 64;
        const int  c0  = (kq ^ lr7) * 8;
        const int  c1  = ((4 + kq) ^ lr7) * 8;

        short8 af[4][2], bf0[2][2], bf1[2][2];

        // ============ phase 1: quadrant (m-half0, n-half0) ============
        #pragma unroll
        for (int mi = 0; mi < 4; ++mi) {
            af[mi][0] = *(const short8*)(a0p + mi * 1024 + c0);
            af[mi][1] = *(const short8*)(a0p + mi * 1024 + c1);
        }
        #pragma unroll
        for (int ni = 0; ni < 2; ++ni) {
            bf0[ni][0] = *(const short8*)(b0p + ni * 1024 + c0);
            bf0[ni][1] = *(const short8*)(b0p + ni * 1024 + c1);
        }
        if (t + 1 < nt) STAGE_A(t + 1, 1);
        __builtin_amdgcn_sched_barrier(0);
        __builtin_amdgcn_s_barrier();
        asm volatile("s_waitcnt lgkmcnt(0)" ::: "memory");
        __builtin_amdgcn_sched_barrier(0);
        __builtin_amdgcn_s_setprio(1);
        #pragma unroll
        for (int ks = 0; ks < 2; ++ks)
            #pragma unroll
            for (int mi = 0; mi < 4; ++mi)
                #pragma unroll
                for (int ni = 0; ni < 2; ++ni)
                    acc[mi][ni] = __builtin_amdgcn_mfma_f32_16x16x32_bf16(
                        af[mi][ks], bf0[ni][ks], acc[mi][ni], 0, 0, 0);
        __builtin_amdgcn_s_setprio(0);
        __builtin_amdgcn_sched_barrier(0);
        __builtin_amdgcn_s_barrier();

        // ============ phase 2: quadrant (m-half0, n-half1) ============
        #pragma unroll
        for (int ni = 0; ni < 2; ++ni) {
            bf1[ni][0] = *(const short8*)(b0p + 8192 + ni * 1024 + c0);
            bf1[ni][1] = *(const short8*)(b0p + 8192 + ni * 1024 + c1);
        }
        if (t + 2 < nt) STAGE_A(t + 2, 0);
        __builtin_amdgcn_sched_barrier(0);
        __builtin_amdgcn_s_barrier();
        asm volatile("s_waitcnt lgkmcnt(0)" ::: "memory");
        __builtin_amdgcn_sched_barrier(0);
        __builtin_amdgcn_s_setprio(1);
        #pragma unroll
        for (int ks = 0; ks < 2; ++ks)
            #pragma unroll
            for (int mi = 0; mi < 4; ++mi)
                #pragma unroll
                for (int ni = 0; ni < 2; ++ni)
                    acc[mi][2 + ni] = __builtin_amdgcn_mfma_f32_16x16x32_bf16(
                        af[mi][ks], bf1[ni][ks], acc[mi][2 + ni], 0, 0, 0);
        __builtin_amdgcn_s_setprio(0);
        __builtin_amdgcn_sched_barrier(0);
        __builtin_amdgcn_s_barrier();

        // ============ phase 3: quadrant (m-half1, n-half0) ============
        #pragma unroll
        for (int mi = 0; mi < 4; ++mi) {
            af[mi][0] = *(const short8*)(a0p + 8192 + mi * 1024 + c0);
            af[mi][1] = *(const short8*)(a0p + 8192 + mi * 1024 + c1);
        }
        if (t + 2 < nt) STAGE_B(t + 2, 0);
        __builtin_amdgcn_sched_barrier(0);
        __builtin_amdgcn_s_barrier();
        asm volatile("s_waitcnt lgkmcnt(0)" ::: "memory");
        __builtin_amdgcn_sched_barrier(0);
        __builtin_amdgcn_s_setprio(1);
        #pragma unroll
        for (int ks = 0; ks < 2; ++ks)
            #pragma unroll
            for (int mi = 0; mi < 4; ++mi)
                #pragma unroll
                for (int ni = 0; ni < 2; ++ni)
                    acc[4 + mi][ni] = __builtin_amdgcn_mfma_f32_16x16x32_bf16(
                        af[mi][ks], bf0[ni][ks], acc[4 + mi][ni], 0, 0, 0);
        __builtin_amdgcn_s_setprio(0);
        __builtin_amdgcn_sched_barrier(0);
        __builtin_amdgcn_s_barrier();

        // ============ phase 4: quadrant (m-half1, n-half1) ============
        if (t + 2 < nt) STAGE_B(t + 2, 1);
        __builtin_amdgcn_sched_barrier(0);
        __builtin_amdgcn_s_barrier();
        __builtin_amdgcn_s_setprio(1);
        #pragma unroll
        for (int ks = 0; ks < 2; ++ks)
            #pragma unroll
            for (int mi = 0; mi < 4; ++mi)
                #pragma unroll
                for (int ni = 0; ni < 2; ++ni)
                    acc[4 + mi][2 + ni] = __builtin_amdgcn_mfma_f32_16x16x32_bf16(
                        af[mi][ks], bf1[ni][ks], acc[4 + mi][2 + ni], 0, 0, 0);
        __builtin_amdgcn_s_setprio(0);
        if (t + 2 < nt)      { asm volatile("s_waitcnt vmcnt(6)" ::: "memory"); }
        else if (t + 1 < nt) { asm volatile("s_waitcnt vmcnt(0)" ::: "memory"); }
        __builtin_amdgcn_sched_barrier(0);
        __builtin_amdgcn_s_barrier();
    }

    // epilogue: C/D layout col=lane&15, row=(lane>>4)*4+i
    const int rbase = m0 + wr * 128 + kq * 4;
    const int cbase = n0 + wc * 64 + lr;
    #pragma unroll
    for (int ni = 0; ni < 4; ++ni) {
        const int c = cbase + ni * 16;
        const float bvf = bias ? bias[c] : 0.0f;
        #pragma unroll
        for (int mi = 0; mi < 8; ++mi) {
            const int r = rbase + mi * 16;
            #pragma unroll
            for (int i = 0; i < 4; ++i) {
                float v = acc[mi][ni][i] + bvf;
                if (RELU) v = fmaxf(v, 0.0f);
                const size_t off = (size_t)(r + i) * N + c;
                if (OUTBF) ((u16*)Cv)[off] = f2b(v);
                else       ((float*)Cv)[off] = v;
            }
        }
    }
}

// ---------------------------------------------------------------------------
// MFMA flash attention: block per (q-tile 64, h, b). 256 threads = 4 waves.
// ---------------------------------------------------------------------------
#define AST 76
__global__ __launch_bounds__(256) void attn_mfma(
    const u16* __restrict__ qkv, u16* __restrict__ O)
{
    const int tid = threadIdx.x;
    const int qi = blockIdx.x;
    const int h  = blockIdx.y;
    const int b  = blockIdx.z;
    const int q0 = qi * 64;

    __shared__ u16 Ks[64 * AST];
    __shared__ u16 Vt[64 * AST];
    __shared__ u16 Ps[64 * AST];   // doubles as Q staging buffer

    const int lane = tid & 63;
    const int w    = tid >> 6;
    const int lr   = lane & 15;
    const int lk   = lane >> 4;

    const int sr = tid >> 2;
    const int sc = tid & 3;

    {
        const u16* src = qkv + (size_t)(b * TT + q0 + sr) * 2304 + h * 64 + sc * 16;
        *(ushort8v*)&Ps[sr * AST + sc * 16]     = *(const ushort8v*)src;
        *(ushort8v*)&Ps[sr * AST + sc * 16 + 8] = *(const ushort8v*)(src + 8);
    }
    __syncthreads();
    short8 aq[2];
    #pragma unroll
    for (int ks = 0; ks < 2; ks++)
        aq[ks] = *(const short8*)&Ps[(w * 16 + lr) * AST + lk * 8 + ks * 32];

    f32x4 oacc[4] = {};
    float m_run[4], l_run[4];
    #pragma unroll
    for (int i = 0; i < 4; i++) { m_run[i] = -3.0e38f; l_run[i] = 0.0f; }

    const int qrow = q0 + w * 16 + lk * 4;
    const int ntile = qi + 1;

    for (int t = 0; t < ntile; t++) {
        const int k0 = t * 64;
        __syncthreads();
        {
            const u16* ksrc = qkv + (size_t)(b * TT + k0 + sr) * 2304 + 768 + h * 64 + sc * 16;
            *(ushort8v*)&Ks[sr * AST + sc * 16]     = *(const ushort8v*)ksrc;
            *(ushort8v*)&Ks[sr * AST + sc * 16 + 8] = *(const ushort8v*)(ksrc + 8);
            const u16* vsrc = ksrc + 768;
            ushort8v v0 = *(const ushort8v*)vsrc;
            ushort8v v1 = *(const ushort8v*)(vsrc + 8);
            #pragma unroll
            for (int j = 0; j < 8; j++) Vt[(sc * 16 + j) * AST + sr]     = v0[j];
            #pragma unroll
            for (int j = 0; j < 8; j++) Vt[(sc * 16 + 8 + j) * AST + sr] = v1[j];
        }
        __syncthreads();

        f32x4 sfrag[4] = {};
        #pragma unroll
        for (int ks = 0; ks < 2; ks++)
            #pragma unroll
            for (int nt = 0; nt < 4; nt++) {
                short8 bk = *(const short8*)&Ks[(nt * 16 + lr) * AST + lk * 8 + ks * 32];
                sfrag[nt] = __builtin_amdgcn_mfma_f32_16x16x32_bf16(aq[ks], bk, sfrag[nt], 0, 0, 0);
            }

        float sv[4][4];
        #pragma unroll
        for (int i = 0; i < 4; i++) {
            float mx = -3.0e38f;
            #pragma unroll
            for (int nt = 0; nt < 4; nt++) {
                float s = sfrag[nt][i] * 0.125f;
                if (t == qi && (k0 + nt * 16 + lr) > (qrow + i)) s = -3.0e38f;
                sv[i][nt] = s;
                mx = fmaxf(mx, s);
            }
            mx = fmaxf(mx, __shfl_xor(mx, 1));
            mx = fmaxf(mx, __shfl_xor(mx, 2));
            mx = fmaxf(mx, __shfl_xor(mx, 4));
            mx = fmaxf(mx, __shfl_xor(mx, 8));
            const float m_new = fmaxf(m_run[i], mx);
            const float scale = __expf(m_run[i] - m_new);
            float rs = 0.0f;
            #pragma unroll
            for (int nt = 0; nt < 4; nt++) {
                float p = __expf(sv[i][nt] - m_new);
                sv[i][nt] = p;
                rs += p;
            }
            rs += __shfl_xor(rs, 1);
            rs += __shfl_xor(rs, 2);
            rs += __shfl_xor(rs, 4);
            rs += __shfl_xor(rs, 8);
            l_run[i] = l_run[i] * scale + rs;
            m_run[i] = m_new;
            #pragma unroll
            for (int dt = 0; dt < 4; dt++) oacc[dt][i] *= scale;
        }

        #pragma unroll
        for (int i = 0; i < 4; i++)
            #pragma unroll
            for (int nt = 0; nt < 4; nt++)
                Ps[(w * 16 + lk * 4 + i) * AST + nt * 16 + lr] = f2b(sv[i][nt]);
        __syncthreads();

        #pragma unroll
        for (int ks = 0; ks < 2; ks++) {
            short8 ap = *(const short8*)&Ps[(w * 16 + lr) * AST + lk * 8 + ks * 32];
            #pragma unroll
            for (int dt = 0; dt < 4; dt++) {
                short8 bv = *(const short8*)&Vt[(dt * 16 + lr) * AST + lk * 8 + ks * 32];
                oacc[dt] = __builtin_amdgcn_mfma_f32_16x16x32_bf16(ap, bv, oacc[dt], 0, 0, 0);
            }
        }
    }

    #pragma unroll
    for (int i = 0; i < 4; i++) {
        const float inv = 1.0f / l_run[i];
        u16* dst = O + (size_t)(b * TT + q0 + w * 16 + lk * 4 + i) * 768 + h * 64 + lr;
        #pragma unroll
        for (int dt = 0; dt < 4; dt++)
            dst[dt * 16] = f2b(oacc[dt][i] * inv);
    }
}

// ---------------------------------------------------------------------------
// Host-side launch
// ---------------------------------------------------------------------------
extern "C" void kernel_launch(void* const* d_in, const int* in_sizes, int n_in,
                              void* d_out, int out_size, void* d_ws, size_t ws_size,
                              hipStream_t stream)
{
    (void)in_sizes; (void)n_in; (void)out_size; (void)ws_size;

    const int*   idx     = (const int*)  d_in[0];
    const float* tok_emb = (const float*)d_in[1];
    const float* pos_emb = (const float*)d_in[2];
    const float* ln1_w   = (const float*)d_in[3];
    const float* ln1_b   = (const float*)d_in[4];
    const float* wq      = (const float*)d_in[5];
    const float* wk      = (const float*)d_in[6];
    const float* wv      = (const float*)d_in[7];
    const float* wo      = (const float*)d_in[8];
    const float* bo      = (const float*)d_in[9];
    const float* ln2_w   = (const float*)d_in[10];
    const float* ln2_b   = (const float*)d_in[11];
    const float* w1      = (const float*)d_in[12];
    const float* b1      = (const float*)d_in[13];
    const float* w2      = (const float*)d_in[14];
    const float* b2      = (const float*)d_in[15];
    const float* lnf_w   = (const float*)d_in[16];
    const float* lnf_b   = (const float*)d_in[17];
    const float* head_w  = (const float*)d_in[18];
    const float* head_b  = (const float*)d_in[19];
    float* out = (float*)d_out;

    // workspace carve: ~112 MB
    const size_t S = (size_t)BT * EE;                 // 3,145,728
    float* x   = (float*)d_ws;                        // f32 [BT,768]
    u16*  qkv  = (u16*)(x + S);                       // bf16 [BT,2304]
    u16*  hb   = qkv + (size_t)BT * 2304;             // bf16 [BT,768]
    u16*  ffh  = hb + S;                              // bf16 [BT,3072]
    u16*  wt   = ffh + (size_t)BT * 3072;             // bf16 weights, reused per layer

    embed_kernel<<<BT * EE / 256, 256, 0, stream>>>(idx, tok_emb, pos_emb, x);

    for (int l = 0; l < L_LAYERS; l++) {
        const size_t oE  = (size_t)l * EE;
        const size_t oEE = (size_t)l * EE * EE;
        const size_t oEF = (size_t)l * EE * 4 * EE;

        // weight prep: all 6 matrices of this layer in one dispatch
        transpose_layer<<<6912, 256, 0, stream>>>(
            wq + oEE, wk + oEE, wv + oEE, wo + oEE, w1 + oEF, w2 + oEF, wt);

        // h = LN1(x)
        ln_kernel<<<BT, 256, 0, stream>>>(x, ln1_w + oE, ln1_b + oE, hb);
        // qkv = h @ [Wq|Wk|Wv]   (bf16 out) — 16x9 = 144 blocks, 8-phase
        gemm8p<0, 1><<<dim3(BT / 256, 2304 / 256), 512, 0, stream>>>(
            hb, wt, nullptr, qkv, BT, 2304, 768);
        // h = attention(qkv)  — MFMA flash
        attn_mfma<<<dim3(TT / 64, HH, BB), 256, 0, stream>>>(qkv, hb);
        // x = x + h @ Wo + bo   (TM=64: 384 blocks)
        gemm_bf16<0, 1, 0, 2><<<dim3(BT / 64, 768 / 128), 256, 0, stream>>>(
            hb, wt + (size_t)3 * 768 * 768, bo + oE, x, x, BT, 768, 768);
        // h = LN2(x)
        ln_kernel<<<BT, 256, 0, stream>>>(x, ln2_w + oE, ln2_b + oE, hb);
        // ffh = relu(h @ W1 + b1)  (bf16 out) — 16x12 = 192 blocks, 8-phase
        gemm8p<1, 1><<<dim3(BT / 256, 3072 / 256), 512, 0, stream>>>(
            hb, wt + (size_t)4 * 768 * 768, b1 + (size_t)l * 4 * EE, ffh, BT, 3072, 768);
        // x = x + ffh @ W2 + b2   (TM=64: 384 blocks)
        gemm_bf16<0, 1, 0, 2><<<dim3(BT / 64, 768 / 128), 256, 0, stream>>>(
            ffh, wt + (size_t)4 * 768 * 768 + (size_t)3072 * 768, b2 + oE, x, x, BT, 768, 3072);
    }

    // final LN + head
    ln_kernel<<<BT, 256, 0, stream>>>(x, lnf_w, lnf_b, hb);
    transpose_cvt<<<dim3(VV / 32, EE / 32), 256, 0, stream>>>(head_w, wt, EE, VV);
    // head: 16x125 = 2000 blocks, 8-phase
    gemm8p<0, 0><<<dim3(BT / 256, VV / 256), 512, 0, stream>>>(
        hb, wt, head_b, out, BT, VV, 768);
}

// Round 7
// 1531.815 us; speedup vs baseline: 1.1015x; 1.0652x over previous
//
#include <hip/hip_runtime.h>
#include <hip/hip_bf16.h>
#include <math.h>

// Problem constants (SimpleLM): L=6, B=4, T=1024, V=32000, E=768, H=12, D=64
#define L_LAYERS 6
#define BB 4
#define TT 1024
#define VV 32000
#define EE 768
#define HH 12
#define DD 64
#define BT (BB * TT)          // 4096 rows of activations

typedef unsigned short u16;
typedef unsigned int   u32;
typedef __attribute__((ext_vector_type(8))) short short8;
typedef __attribute__((ext_vector_type(8))) unsigned short ushort8v;
typedef __attribute__((ext_vector_type(4))) float f32x4;

__device__ __forceinline__ float b2f_lo(u32 u) { union { u32 i; float f; } c; c.i = u << 16;          return c.f; }
__device__ __forceinline__ float b2f_hi(u32 u) { union { u32 i; float f; } c; c.i = u & 0xffff0000u;  return c.f; }
__device__ __forceinline__ u16  f2b(float f)   { union { float f; u32 i; } c{f}; u32 r = c.i + 0x7fffu + ((c.i >> 16) & 1u); return (u16)(r >> 16); }

__device__ __forceinline__ void gload16(const void* g, void* l) {
    __builtin_amdgcn_global_load_lds(
        (const __attribute__((address_space(1))) void*)g,
        (__attribute__((address_space(3))) void*)l, 16, 0, 0);
}

// ---------------------------------------------------------------------------
// Embedding: x[b,t,e] = tok_emb[idx[b,t], e] + pos_emb[t, e]  (f32 out)
// ---------------------------------------------------------------------------
__global__ __launch_bounds__(256) void embed_kernel(
    const int* __restrict__ idx, const float* __restrict__ tok_emb,
    const float* __restrict__ pos_emb, float* __restrict__ x)
{
    int i = blockIdx.x * 256 + threadIdx.x;          // < BT*EE
    int e  = i % EE;
    int bt = i / EE;
    int t  = bt % TT;
    int tok = idx[bt];
    x[i] = tok_emb[(size_t)tok * EE + e] + pos_emb[(size_t)t * EE + e];
}

// ---------------------------------------------------------------------------
// LayerNorm over last dim (E=768). f32 in, bf16 out. One block per row.
// ---------------------------------------------------------------------------
__global__ __launch_bounds__(256) void ln_kernel(
    const float* __restrict__ X, const float* __restrict__ w,
    const float* __restrict__ b, u16* __restrict__ Y)
{
    const int tid = threadIdx.x;
    const size_t row = blockIdx.x;
    const float* x = X + row * EE;

    float v0 = x[tid], v1 = x[tid + 256], v2 = x[tid + 512];

    __shared__ float red[256];
    red[tid] = v0 + v1 + v2;
    __syncthreads();
    for (int off = 128; off > 0; off >>= 1) {
        if (tid < off) red[tid] += red[tid + off];
        __syncthreads();
    }
    float mean = red[0] * (1.0f / EE);
    __syncthreads();
    float d0 = v0 - mean, d1 = v1 - mean, d2 = v2 - mean;
    red[tid] = d0 * d0 + d1 * d1 + d2 * d2;
    __syncthreads();
    for (int off = 128; off > 0; off >>= 1) {
        if (tid < off) red[tid] += red[tid + off];
        __syncthreads();
    }
    float rstd = rsqrtf(red[0] * (1.0f / EE) + 1e-5f);

    u16* y = Y + row * EE;
    y[tid]       = f2b(d0 * rstd * w[tid]       + b[tid]);
    y[tid + 256] = f2b(d1 * rstd * w[tid + 256] + b[tid + 256]);
    y[tid + 512] = f2b(d2 * rstd * w[tid + 512] + b[tid + 512]);
}

// ---------------------------------------------------------------------------
// Transpose + convert 32x32 tile core: W f32 [K,N] -> Wt bf16 [N,K]
// ---------------------------------------------------------------------------
__device__ __forceinline__ void transpose_tile(
    const float* __restrict__ W, u16* __restrict__ Wt,
    int K, int N, int kt, int nt)
{
    __shared__ float t[32][33];
    const int k0 = kt * 32;
    const int n0 = nt * 32;
    const int c = threadIdx.x & 31;
    const int r = threadIdx.x >> 5;   // 0..7
    #pragma unroll
    for (int i = 0; i < 4; i++)
        t[r + i * 8][c] = W[(size_t)(k0 + r + i * 8) * N + n0 + c];
    __syncthreads();
    #pragma unroll
    for (int i = 0; i < 4; i++) {
        int rr = r + i * 8;
        Wt[(size_t)(n0 + rr) * K + k0 + c] = f2b(t[c][rr]);
    }
}

// Single-matrix transpose (used for head_w)
__global__ __launch_bounds__(256) void transpose_cvt(
    const float* __restrict__ W, u16* __restrict__ Wt, int K, int N)
{
    transpose_tile(W, Wt, K, N, blockIdx.y, blockIdx.x);
}

// Batched per-layer transpose: wq,wk,wv,wo (768x768 each), w1 (768x3072),
// w2 (3072x768) -> wt = [wqT|wkT|wvT|woT|w1T|w2T]. 6912 tiles total.
__global__ __launch_bounds__(256) void transpose_layer(
    const float* __restrict__ wq, const float* __restrict__ wk,
    const float* __restrict__ wv, const float* __restrict__ wo,
    const float* __restrict__ w1, const float* __restrict__ w2,
    u16* __restrict__ wt)
{
    const int t = blockIdx.x;
    if (t < 2304) {                       // 4 x (768x768), 576 tiles each
        const int m = t / 576, r = t % 576;
        const float* Ws[4] = {wq, wk, wv, wo};
        transpose_tile(Ws[m], wt + (size_t)m * 768 * 768, 768, 768, r / 24, r % 24);
    } else if (t < 4608) {                // w1: K=768, N=3072 -> w1T [3072,768]
        const int r = t - 2304;
        transpose_tile(w1, wt + (size_t)4 * 768 * 768, 768, 3072, r / 96, r % 96);
    } else {                              // w2: K=3072, N=768 -> w2T [768,3072]
        const int r = t - 4608;
        transpose_tile(w2, wt + (size_t)4 * 768 * 768 + (size_t)3072 * 768,
                       3072, 768, r / 24, r % 24);
    }
}

// ---------------------------------------------------------------------------
// bf16 MFMA GEMM (128-wide tiles): C = A @ Bt^T (+bias)(+res)(+relu)
// m97-style 2-barrier loop, proven config. VECST=1 (head): f32 output
// repacked through LDS and stored as dwordx4 (needs MFRAG=4, OUTBF=0).
// ---------------------------------------------------------------------------
template<int RELU, int RES, int OUTBF, int MFRAG, int VECST>
__global__ __launch_bounds__(256) void gemm_bf16(
    const u16* __restrict__ A, const u16* __restrict__ Bt,
    const float* __restrict__ bias, const float* __restrict__ res,
    void* __restrict__ Cv, int M, int N, int K)
{
    constexpr int TM = MFRAG * 32;
    __shared__ u16 SH[(TM + 128) * 64];
    u16* As = SH;
    u16* Bs = SH + TM * 64;

    const int tid  = threadIdx.x;
    const int lane = tid & 63;
    const int w    = tid >> 6;
    const int wr   = w >> 1, wc = w & 1;
    const int m0 = blockIdx.x * TM;     // M is the fast grid dim
    const int n0 = blockIdx.y * 128;

    const int cs = (lane & 7) ^ (lane >> 3);
    const int rl = lane >> 3;

    int aoff[2 * MFRAG], boff[8];
    const int kq = lane >> 4;
    #pragma unroll
    for (int mi = 0; mi < MFRAG; mi++) {
        int rg = wr * (MFRAG * 16) + mi * 16 + (lane & 15);
        #pragma unroll
        for (int ks = 0; ks < 2; ks++)
            aoff[2 * mi + ks] = rg * 64 + (((ks * 4 + kq) ^ (rg & 7)) * 8);
    }
    #pragma unroll
    for (int ni = 0; ni < 4; ni++) {
        int rg = wc * 64 + ni * 16 + (lane & 15);
        #pragma unroll
        for (int ks = 0; ks < 2; ks++)
            boff[2 * ni + ks] = rg * 64 + (((ks * 4 + kq) ^ (rg & 7)) * 8);
    }

    f32x4 acc[MFRAG][4] = {};

    for (int k0 = 0; k0 < K; k0 += 64) {
        __syncthreads();
        #pragma unroll
        for (int i = 0; i < MFRAG; i++) {
            const int seg = i * 4 + w;
            const int row = seg * 8 + rl;
            gload16(A + (size_t)(m0 + row) * K + k0 + cs * 8, &As[seg * 512]);
        }
        #pragma unroll
        for (int i = 0; i < 4; i++) {
            const int seg = i * 4 + w;
            const int row = seg * 8 + rl;
            gload16(Bt + (size_t)(n0 + row) * K + k0 + cs * 8, &Bs[seg * 512]);
        }
        __syncthreads();
        #pragma unroll
        for (int ks = 0; ks < 2; ks++) {
            short8 af[MFRAG], bfv[4];
            #pragma unroll
            for (int mi = 0; mi < MFRAG; mi++) af[mi] = *(const short8*)&As[aoff[2 * mi + ks]];
            #pragma unroll
            for (int ni = 0; ni < 4; ni++) bfv[ni] = *(const short8*)&Bs[boff[2 * ni + ks]];
            #pragma unroll
            for (int mi = 0; mi < MFRAG; mi++)
                #pragma unroll
                for (int ni = 0; ni < 4; ni++)
                    acc[mi][ni] = __builtin_amdgcn_mfma_f32_16x16x32_bf16(
                        af[mi], bfv[ni], acc[mi][ni], 0, 0, 0);
        }
    }

    const int rbase = m0 + wr * (MFRAG * 16) + (lane >> 4) * 4;
    const int cbase = n0 + wc * 64 + (lane & 15);

    if (VECST) {
        // f32 output repacked through LDS -> dwordx4 stores (MFRAG==4 only)
        __syncthreads();                 // main-loop LDS reads done
        float* CF = (float*)SH;          // 64 x 128 f32 = 32 KB
        #pragma unroll
        for (int ch = 0; ch < 2; ++ch) {
            if (wr == ch) {
                #pragma unroll
                for (int ni = 0; ni < 4; ni++) {
                    const int c = cbase + ni * 16;
                    const float bvf = bias ? bias[c] : 0.0f;
                    #pragma unroll
                    for (int mi = 0; mi < MFRAG; mi++)
                        #pragma unroll
                        for (int i = 0; i < 4; i++)
                            CF[(mi * 16 + kq * 4 + i) * 128 + wc * 64 + ni * 16 + (lane & 15)]
                                = acc[mi][ni][i] + bvf;
                }
            }
            __syncthreads();
            const int rr = tid >> 5;            // 0..7
            const int cc = (tid & 31) * 4;      // 0..124
            #pragma unroll
            for (int j = 0; j < 8; ++j) {
                const int r = rr + j * 8;       // 0..63
                *(f32x4*)&((float*)Cv)[(size_t)(m0 + ch * 64 + r) * N + n0 + cc]
                    = *(const f32x4*)&CF[r * 128 + cc];
            }
            if (ch == 0) __syncthreads();
        }
    } else {
        #pragma unroll
        for (int ni = 0; ni < 4; ni++) {
            const int c = cbase + ni * 16;
            const float bv = bias ? bias[c] : 0.0f;
            #pragma unroll
            for (int mi = 0; mi < MFRAG; mi++) {
                const int r = rbase + mi * 16;
                #pragma unroll
                for (int i = 0; i < 4; i++) {
                    float v = acc[mi][ni][i] + bv;
                    const size_t off = (size_t)(r + i) * N + c;
                    if (RES)  v += res[off];
                    if (RELU) v = fmaxf(v, 0.0f);
                    if (OUTBF) ((u16*)Cv)[off] = f2b(v);
                    else       ((float*)Cv)[off] = v;
                }
            }
        }
    }
}

// ---------------------------------------------------------------------------
// MFMA flash attention v2: block per (q-tile 64, h, b). 256 threads = 4 waves.
// K double-buffered via global_load_lds + XOR chunk swizzle (b128-aligned,
// stride 64). V prefetched to regs during QK^T, transposed into LDS (paired
// u32 writes) after PV. One barrier per tile (P tile is wave-private).
// Defer-max (T13): skip O/l rescale when wave-wide max growth <= 8.
// ---------------------------------------------------------------------------
#define AST 72
__global__ __launch_bounds__(256) void attn_mfma(
    const u16* __restrict__ qkv, u16* __restrict__ O)
{
    const int tid = threadIdx.x;
    const int qi = blockIdx.x;
    const int h  = blockIdx.y;
    const int b  = blockIdx.z;
    const int q0 = qi * 64;

    __shared__ u16 Ks[2][64 * 64];     // swizzled, b128-aligned rows
    __shared__ u16 Vt[2][64 * AST];    // V^T [d][k]
    __shared__ u16 Ps[64 * AST];       // Q staging, then P tile (wave-private rows)

    const int lane = tid & 63;
    const int w    = tid >> 6;
    const int lr   = lane & 15;
    const int lk   = lane >> 4;        // k-group 0..3

    // K staging lanes (GEMM pattern)
    const int cs = (lane & 7) ^ (lane >> 3);
    const int rl = lane >> 3;
    // V staging lanes (pair-write)
    const int vk2 = tid & 31;          // k-pair index (k = 2*vk2, 2*vk2+1)
    const int vdc = tid >> 5;          // d-chunk 0..7 (8 d's each)

    // ---- stage Q into Ps, hoist A-fragments ----
    {
        const int sr = tid >> 2, sc = tid & 3;
        const u16* src = qkv + (size_t)(b * TT + q0 + sr) * 2304 + h * 64 + sc * 16;
        *(ushort8v*)&Ps[sr * AST + sc * 16]     = *(const ushort8v*)src;
        *(ushort8v*)&Ps[sr * AST + sc * 16 + 8] = *(const ushort8v*)(src + 8);
    }
    __syncthreads();
    short8 aq[2];
    #pragma unroll
    for (int ks = 0; ks < 2; ks++)
        aq[ks] = *(const short8*)&Ps[(w * 16 + lr) * AST + lk * 8 + ks * 32];

    ushort8v vr0, vr1;
    auto K_ISSUE = [&](int t, int bf) {
        const int k0 = t * 64;
        #pragma unroll
        for (int j = 0; j < 2; ++j) {
            const int seg = j * 4 + w;         // 0..7
            const int row = seg * 8 + rl;
            gload16(qkv + (size_t)(b * TT + k0 + row) * 2304 + 768 + h * 64 + cs * 8,
                    &Ks[bf][seg * 512]);
        }
    };
    auto V_LOAD = [&](int t) {
        const int k0 = t * 64;
        const u16* p = qkv + (size_t)(b * TT + k0 + 2 * vk2) * 2304 + 1536 + h * 64 + vdc * 8;
        vr0 = *(const ushort8v*)p;
        vr1 = *(const ushort8v*)(p + 2304);
    };
    auto V_WRITE = [&](int bf) {
        #pragma unroll
        for (int j = 0; j < 8; ++j) {
            const u32 val = (u32)vr0[j] | ((u32)vr1[j] << 16);
            *(u32*)&Vt[bf][(vdc * 8 + j) * AST + 2 * vk2] = val;
        }
    };

    // ---- prologue: tile 0 ----
    K_ISSUE(0, 0);
    V_LOAD(0);
    V_WRITE(0);
    __syncthreads();

    f32x4 oacc[4] = {};
    float m_run[4], l_run[4];
    #pragma unroll
    for (int i = 0; i < 4; i++) { m_run[i] = -3.0e38f; l_run[i] = 0.0f; }

    const int qrow = q0 + w * 16 + lk * 4;

    for (int t = 0; t <= qi; ++t) {
        const int cur = t & 1;

        // ---- QK^T ----
        f32x4 sfrag[4] = {};
        #pragma unroll
        for (int ks = 0; ks < 2; ks++)
            #pragma unroll
            for (int nt = 0; nt < 4; nt++) {
                const int rg = nt * 16 + lr;
                short8 bk = *(const short8*)&Ks[cur][rg * 64 + (((ks * 4 + lk) ^ (rg & 7)) * 8)];
                sfrag[nt] = __builtin_amdgcn_mfma_f32_16x16x32_bf16(aq[ks], bk, sfrag[nt], 0, 0, 0);
            }

        // ---- prefetch next tile (K -> LDS dbuf, V -> regs) ----
        if (t < qi) { K_ISSUE(t + 1, cur ^ 1); V_LOAD(t + 1); }

        // ---- softmax (defer-max) ----
        const int k0 = t * 64;
        float sv[4][4], mxv[4];
        float need = 0.0f;
        #pragma unroll
        for (int i = 0; i < 4; i++) {
            float mx = -3.0e38f;
            #pragma unroll
            for (int nt = 0; nt < 4; nt++) {
                float s = sfrag[nt][i] * 0.125f;
                if (t == qi && (k0 + nt * 16 + lr) > (qrow + i)) s = -3.0e38f;
                sv[i][nt] = s;
                mx = fmaxf(mx, s);
            }
            mx = fmaxf(mx, __shfl_xor(mx, 1));
            mx = fmaxf(mx, __shfl_xor(mx, 2));
            mx = fmaxf(mx, __shfl_xor(mx, 4));
            mx = fmaxf(mx, __shfl_xor(mx, 8));
            mxv[i] = mx;
            need = fmaxf(need, mx - m_run[i]);
        }
        if (!__all(need <= 8.0f)) {
            #pragma unroll
            for (int i = 0; i < 4; i++) {
                const float m_new = fmaxf(m_run[i], mxv[i]);
                const float scale = __expf(m_run[i] - m_new);
                l_run[i] *= scale;
                #pragma unroll
                for (int dt = 0; dt < 4; dt++) oacc[dt][i] *= scale;
                m_run[i] = m_new;
            }
        }
        #pragma unroll
        for (int i = 0; i < 4; i++) {
            float rs = 0.0f;
            #pragma unroll
            for (int nt = 0; nt < 4; nt++) {
                const float p = __expf(sv[i][nt] - m_run[i]);
                sv[i][nt] = p;
                rs += p;
            }
            rs += __shfl_xor(rs, 1);
            rs += __shfl_xor(rs, 2);
            rs += __shfl_xor(rs, 4);
            rs += __shfl_xor(rs, 8);
            l_run[i] += rs;
        }

        // ---- P (bf16) to LDS — wave-private rows, no barrier needed ----
        #pragma unroll
        for (int i = 0; i < 4; i++)
            #pragma unroll
            for (int nt = 0; nt < 4; nt++)
                Ps[(w * 16 + lk * 4 + i) * AST + nt * 16 + lr] = f2b(sv[i][nt]);

        // ---- PV ----
        #pragma unroll
        for (int ks = 0; ks < 2; ks++) {
            short8 ap = *(const short8*)&Ps[(w * 16 + lr) * AST + lk * 8 + ks * 32];
            #pragma unroll
            for (int dt = 0; dt < 4; dt++) {
                short8 bv = *(const short8*)&Vt[cur][(dt * 16 + lr) * AST + lk * 8 + ks * 32];
                oacc[dt] = __builtin_amdgcn_mfma_f32_16x16x32_bf16(ap, bv, oacc[dt], 0, 0, 0);
            }
        }

        // ---- finish V staging for next tile, single barrier ----
        if (t < qi) V_WRITE(cur ^ 1);
        __syncthreads();
    }

    // ---- epilogue ----
    #pragma unroll
    for (int i = 0; i < 4; i++) {
        const float inv = 1.0f / l_run[i];
        u16* dst = O + (size_t)(b * TT + q0 + w * 16 + lk * 4 + i) * 768 + h * 64 + lr;
        #pragma unroll
        for (int dt = 0; dt < 4; dt++)
            dst[dt * 16] = f2b(oacc[dt][i] * inv);
    }
}

// ---------------------------------------------------------------------------
// Host-side launch
// ---------------------------------------------------------------------------
extern "C" void kernel_launch(void* const* d_in, const int* in_sizes, int n_in,
                              void* d_out, int out_size, void* d_ws, size_t ws_size,
                              hipStream_t stream)
{
    (void)in_sizes; (void)n_in; (void)out_size; (void)ws_size;

    const int*   idx     = (const int*)  d_in[0];
    const float* tok_emb = (const float*)d_in[1];
    const float* pos_emb = (const float*)d_in[2];
    const float* ln1_w   = (const float*)d_in[3];
    const float* ln1_b   = (const float*)d_in[4];
    const float* wq      = (const float*)d_in[5];
    const float* wk      = (const float*)d_in[6];
    const float* wv      = (const float*)d_in[7];
    const float* wo      = (const float*)d_in[8];
    const float* bo      = (const float*)d_in[9];
    const float* ln2_w   = (const float*)d_in[10];
    const float* ln2_b   = (const float*)d_in[11];
    const float* w1      = (const float*)d_in[12];
    const float* b1      = (const float*)d_in[13];
    const float* w2      = (const float*)d_in[14];
    const float* b2      = (const float*)d_in[15];
    const float* lnf_w   = (const float*)d_in[16];
    const float* lnf_b   = (const float*)d_in[17];
    const float* head_w  = (const float*)d_in[18];
    const float* head_b  = (const float*)d_in[19];
    float* out = (float*)d_out;

    // workspace carve: ~112 MB
    const size_t S = (size_t)BT * EE;                 // 3,145,728
    float* x   = (float*)d_ws;                        // f32 [BT,768]
    u16*  qkv  = (u16*)(x + S);                       // bf16 [BT,2304]
    u16*  hb   = qkv + (size_t)BT * 2304;             // bf16 [BT,768]
    u16*  ffh  = hb + S;                              // bf16 [BT,3072]
    u16*  wt   = ffh + (size_t)BT * 3072;             // bf16 weights, reused per layer

    embed_kernel<<<BT * EE / 256, 256, 0, stream>>>(idx, tok_emb, pos_emb, x);

    for (int l = 0; l < L_LAYERS; l++) {
        const size_t oE  = (size_t)l * EE;
        const size_t oEE = (size_t)l * EE * EE;
        const size_t oEF = (size_t)l * EE * 4 * EE;

        // weight prep: all 6 matrices of this layer in one dispatch
        transpose_layer<<<6912, 256, 0, stream>>>(
            wq + oEE, wk + oEE, wv + oEE, wo + oEE, w1 + oEF, w2 + oEF, wt);

        // h = LN1(x)
        ln_kernel<<<BT, 256, 0, stream>>>(x, ln1_w + oE, ln1_b + oE, hb);
        // qkv = h @ [Wq|Wk|Wv]   (bf16 out)
        gemm_bf16<0, 0, 1, 4, 0><<<dim3(BT / 128, 2304 / 128), 256, 0, stream>>>(
            hb, wt, nullptr, nullptr, qkv, BT, 2304, 768);
        // h = attention(qkv)  — MFMA flash v2
        attn_mfma<<<dim3(TT / 64, HH, BB), 256, 0, stream>>>(qkv, hb);
        // x = x + h @ Wo + bo   (TM=64: 384 blocks)
        gemm_bf16<0, 1, 0, 2, 0><<<dim3(BT / 64, 768 / 128), 256, 0, stream>>>(
            hb, wt + (size_t)3 * 768 * 768, bo + oE, x, x, BT, 768, 768);
        // h = LN2(x)
        ln_kernel<<<BT, 256, 0, stream>>>(x, ln2_w + oE, ln2_b + oE, hb);
        // ffh = relu(h @ W1 + b1)  (bf16 out)
        gemm_bf16<1, 0, 1, 4, 0><<<dim3(BT / 128, 3072 / 128), 256, 0, stream>>>(
            hb, wt + (size_t)4 * 768 * 768, b1 + (size_t)l * 4 * EE, nullptr, ffh, BT, 3072, 768);
        // x = x + ffh @ W2 + b2   (TM=64: 384 blocks)
        gemm_bf16<0, 1, 0, 2, 0><<<dim3(BT / 64, 768 / 128), 256, 0, stream>>>(
            ffh, wt + (size_t)4 * 768 * 768 + (size_t)3072 * 768, b2 + oE, x, x, BT, 768, 3072);
    }

    // final LN + head (vectorized f32 epilogue)
    ln_kernel<<<BT, 256, 0, stream>>>(x, lnf_w, lnf_b, hb);
    transpose_cvt<<<dim3(VV / 32, EE / 32), 256, 0, stream>>>(head_w, wt, EE, VV);
    gemm_bf16<0, 0, 0, 4, 1><<<dim3(BT / 128, VV / 128), 256, 0, stream>>>(
        hb, wt, head_b, nullptr, out, BT, VV, 768);
}